// Round 2
// baseline (478.891 us; speedup 1.0000x reference)
//
#include <hip/hip_runtime.h>

// ---------------------------------------------------------------------------
// Strategy: build CSR (bucket edges by dst) on device each call, then do an
// atomic-free gather-sum: one wave per node, lane = feature dim.
// This removes the 78M fp32 atomicAdds (370 MB of RMW write traffic) that
// bounded the round-1 kernel.
// ---------------------------------------------------------------------------

#define SCAN_T 1024

__global__ void hist_kernel(const int* __restrict__ dst, int* __restrict__ counts, int E) {
    int e = blockIdx.x * blockDim.x + threadIdx.x;
    if (e < E) atomicAdd(&counts[dst[e]], 1);
}

// Single-block exclusive scan over N counts -> offsets[N+1], plus cursor copy.
__global__ void scan_kernel(const int* __restrict__ counts,
                            int* __restrict__ offsets,
                            int* __restrict__ cursor, int N) {
    __shared__ int sums[SCAN_T];
    const int tid = threadIdx.x;
    const int chunk = (N + SCAN_T - 1) / SCAN_T;
    const int begin = tid * chunk;
    const int end   = min(begin + chunk, N);

    int local = 0;
    for (int i = begin; i < end; ++i) local += counts[i];
    sums[tid] = local;
    __syncthreads();

    // Hillis-Steele inclusive scan in LDS
    for (int off = 1; off < SCAN_T; off <<= 1) {
        int t = (tid >= off) ? sums[tid - off] : 0;
        __syncthreads();
        sums[tid] += t;
        __syncthreads();
    }

    int run = sums[tid] - local;   // exclusive prefix for this thread's chunk
    for (int i = begin; i < end; ++i) {
        offsets[i] = run;
        cursor[i]  = run;
        run += counts[i];
    }
    if (tid == SCAN_T - 1) offsets[N] = sums[SCAN_T - 1];  // == E
}

// Scatter edge payload (src, e_feat) into dst-ordered buckets.
__global__ void scatter_kernel(const int* __restrict__ src,
                               const float* __restrict__ efeat,
                               const int* __restrict__ dst,
                               int* __restrict__ cursor,
                               int2* __restrict__ pack, int E) {
    int e = blockIdx.x * blockDim.x + threadIdx.x;
    if (e >= E) return;
    int d = dst[e];
    int p = atomicAdd(&cursor[d], 1);
    int2 v;
    v.x = src[e];
    v.y = __float_as_int(efeat[e]);
    pack[p] = v;
}

// One 64-lane wave per node; lane = feature index. Atomic-free accumulate.
__global__ void gather_kernel(const float* __restrict__ gemb,
                              const int2* __restrict__ pack,
                              const int* __restrict__ offsets,
                              float* __restrict__ out, int N) {
    int wid  = (blockIdx.x * blockDim.x + threadIdx.x) >> 6;
    int lane = threadIdx.x & 63;
    if (wid >= N) return;

    int beg = offsets[wid];
    int end = offsets[wid + 1];

    float acc  = 0.f;
    float eacc = 0.f;
    for (int j = beg; j < end; ++j) {
        int2 v = pack[j];                       // wave-uniform 8B load
        acc  += gemb[(long)v.x * 64 + lane];    // coalesced 256B row read
        eacc += __int_as_float(v.y);
    }
    out[(long)wid * 65 + lane] = acc;
    if (lane == 0) out[(long)wid * 65 + 64] = eacc;
}

// Fallback (round-1 atomic version) in case ws_size is too small.
__global__ void atomic_fallback_kernel(const float* __restrict__ gemb,
                                       const float* __restrict__ efeat,
                                       const int* __restrict__ src,
                                       const int* __restrict__ dst,
                                       float* __restrict__ out, int E) {
    int eidx = blockIdx.x * 4 + (threadIdx.x >> 6);
    int lane = threadIdx.x & 63;
    if (eidx >= E) return;
    int s = src[eidx];
    int d = dst[eidx];
    float v = gemb[(long)s * 64 + lane];
    atomicAdd(&out[(long)d * 65 + lane], v);
    if (lane == 0) atomicAdd(&out[(long)d * 65 + 64], efeat[eidx]);
}

extern "C" void kernel_launch(void* const* d_in, const int* in_sizes, int n_in,
                              void* d_out, int out_size, void* d_ws, size_t ws_size,
                              hipStream_t stream) {
    const float* gemb  = (const float*)d_in[0];   // [N, 64]
    const float* efeat = (const float*)d_in[1];   // [E]
    const int*   src   = (const int*)d_in[2];     // [E]
    const int*   dst   = (const int*)d_in[3];     // [E]
    float*       out   = (float*)d_out;           // [N, 65]

    const int N = in_sizes[0] / 64;
    const int E = in_sizes[1];

    // workspace layout (16B aligned chunks)
    size_t off_counts  = 0;
    size_t off_offsets = off_counts  + ((size_t)N * 4 + 15 & ~(size_t)15);
    size_t off_cursor  = off_offsets + (((size_t)(N + 1) * 4 + 15) & ~(size_t)15);
    size_t off_pack    = off_cursor  + ((size_t)N * 4 + 15 & ~(size_t)15);
    size_t needed      = off_pack    + (size_t)E * 8;

    if (ws_size < needed) {
        // not enough scratch: fall back to the atomic version
        hipMemsetAsync(d_out, 0, (size_t)out_size * sizeof(float), stream);
        int blocks = (E + 3) / 4;
        atomic_fallback_kernel<<<blocks, 256, 0, stream>>>(gemb, efeat, src, dst, out, E);
        return;
    }

    char* ws = (char*)d_ws;
    int*  counts  = (int*)(ws + off_counts);
    int*  offsets = (int*)(ws + off_offsets);
    int*  cursor  = (int*)(ws + off_cursor);
    int2* pack    = (int2*)(ws + off_pack);

    hipMemsetAsync(counts, 0, (size_t)N * 4, stream);

    int eblocks = (E + 255) / 256;
    hist_kernel<<<eblocks, 256, 0, stream>>>(dst, counts, E);
    scan_kernel<<<1, SCAN_T, 0, stream>>>(counts, offsets, cursor, N);
    scatter_kernel<<<eblocks, 256, 0, stream>>>(src, efeat, dst, cursor, pack, E);

    int nblocks = (N + 3) / 4;   // 4 waves (nodes) per 256-thread block
    gather_kernel<<<nblocks, 256, 0, stream>>>(gemb, pack, offsets, out, N);
}

// Round 3
// 230.334 us; speedup vs baseline: 2.0791x; 2.0791x over previous
//
#include <hip/hip_runtime.h>

// ---------------------------------------------------------------------------
// CSR build (hist -> hierarchical scan -> scatter) + atomic-free gather-sum.
// Round-3 change: replace the 230us single-block scan with a 3-kernel
// device-wide scan; vectorize hist/scatter; unroll gather 2x.
// ---------------------------------------------------------------------------

#define SCAN_ELEMS   1024   // counts per scan block
#define SCAN_THREADS 256    // 4 counts per thread

__global__ void hist_kernel(const int* __restrict__ dst, int* __restrict__ counts, int E) {
    int i = (blockIdx.x * blockDim.x + threadIdx.x) * 4;
    if (i + 3 < E) {
        int4 d = *(const int4*)(dst + i);
        atomicAdd(&counts[d.x], 1);
        atomicAdd(&counts[d.y], 1);
        atomicAdd(&counts[d.z], 1);
        atomicAdd(&counts[d.w], 1);
    } else {
        for (int k = i; k < E; ++k) atomicAdd(&counts[dst[k]], 1);
    }
}

// Phase A: per-block sums of 1024 counts each.
__global__ void scan_block_sums(const int* __restrict__ counts,
                                int* __restrict__ bsums, int N) {
    __shared__ int red[SCAN_THREADS];
    int tid  = threadIdx.x;
    int base = blockIdx.x * SCAN_ELEMS + tid * 4;
    int s = 0;
    if (base + 3 < N) {
        int4 c = *(const int4*)(counts + base);
        s = c.x + c.y + c.z + c.w;
    } else {
        int lim = min(base + 4, N);
        for (int k = base; k < lim; ++k) s += counts[k];
    }
    red[tid] = s;
    __syncthreads();
    for (int off = SCAN_THREADS / 2; off > 0; off >>= 1) {
        if (tid < off) red[tid] += red[tid + off];
        __syncthreads();
    }
    if (tid == 0) bsums[blockIdx.x] = red[0];
}

// Phase B: one small block scans the B block-sums (exclusive, in place),
// and writes offsets[N] = total (= E).
__global__ void scan_top(int* __restrict__ bsums, int* __restrict__ offsets_N, int B) {
    __shared__ int sh[128];
    int t = threadIdx.x;
    int v = (t < B) ? bsums[t] : 0;
    sh[t] = v;
    __syncthreads();
    for (int off = 1; off < 128; off <<= 1) {
        int u = (t >= off) ? sh[t - off] : 0;
        __syncthreads();
        sh[t] += u;
        __syncthreads();
    }
    if (t < B) bsums[t] = sh[t] - v;          // exclusive
    if (t == 127) offsets_N[0] = sh[127];     // total
}

// Phase C: local exclusive scan per block + block base -> offsets & cursor.
__global__ void scan_final(const int* __restrict__ counts,
                           const int* __restrict__ bsums,
                           int* __restrict__ offsets,
                           int* __restrict__ cursor, int N) {
    __shared__ int sh[SCAN_THREADS];
    int tid  = threadIdx.x;
    int base = blockIdx.x * SCAN_ELEMS + tid * 4;
    int4 c = make_int4(0, 0, 0, 0);
    if (base + 3 < N) {
        c = *(const int4*)(counts + base);
    } else {
        if (base + 0 < N) c.x = counts[base + 0];
        if (base + 1 < N) c.y = counts[base + 1];
        if (base + 2 < N) c.z = counts[base + 2];
    }
    int tsum = c.x + c.y + c.z + c.w;
    sh[tid] = tsum;
    __syncthreads();
    for (int off = 1; off < SCAN_THREADS; off <<= 1) {
        int u = (tid >= off) ? sh[tid - off] : 0;
        __syncthreads();
        sh[tid] += u;
        __syncthreads();
    }
    int excl = sh[tid] - tsum;
    int b0 = bsums[blockIdx.x] + excl;
    int4 o;
    o.x = b0;
    o.y = o.x + c.x;
    o.z = o.y + c.y;
    o.w = o.z + c.z;
    if (base + 3 < N) {
        *(int4*)(offsets + base) = o;
        *(int4*)(cursor  + base) = o;
    } else {
        if (base + 0 < N) { offsets[base + 0] = o.x; cursor[base + 0] = o.x; }
        if (base + 1 < N) { offsets[base + 1] = o.y; cursor[base + 1] = o.y; }
        if (base + 2 < N) { offsets[base + 2] = o.z; cursor[base + 2] = o.z; }
    }
}

// Scatter edge payload (src, e_feat) into dst-ordered buckets. 4 edges/thread.
__global__ void scatter_kernel(const int* __restrict__ src,
                               const float* __restrict__ efeat,
                               const int* __restrict__ dst,
                               int* __restrict__ cursor,
                               int2* __restrict__ pack, int E) {
    int i = (blockIdx.x * blockDim.x + threadIdx.x) * 4;
    if (i + 3 < E) {
        int4   s = *(const int4*)(src + i);
        float4 f = *(const float4*)(efeat + i);
        int4   d = *(const int4*)(dst + i);
        int p;
        p = atomicAdd(&cursor[d.x], 1); pack[p] = make_int2(s.x, __float_as_int(f.x));
        p = atomicAdd(&cursor[d.y], 1); pack[p] = make_int2(s.y, __float_as_int(f.y));
        p = atomicAdd(&cursor[d.z], 1); pack[p] = make_int2(s.z, __float_as_int(f.z));
        p = atomicAdd(&cursor[d.w], 1); pack[p] = make_int2(s.w, __float_as_int(f.w));
    } else {
        for (int k = i; k < E; ++k) {
            int p = atomicAdd(&cursor[dst[k]], 1);
            pack[p] = make_int2(src[k], __float_as_int(efeat[k]));
        }
    }
}

// One 64-lane wave per node; lane = feature index. Atomic-free, 2-way unroll.
__global__ void gather_kernel(const float* __restrict__ gemb,
                              const int2* __restrict__ pack,
                              const int* __restrict__ offsets,
                              float* __restrict__ out, int N) {
    int wid  = (blockIdx.x * blockDim.x + threadIdx.x) >> 6;
    int lane = threadIdx.x & 63;
    if (wid >= N) return;

    int beg = offsets[wid];
    int end = offsets[wid + 1];

    float acc0 = 0.f, acc1 = 0.f, e0 = 0.f, e1 = 0.f;
    int j = beg;
    for (; j + 1 < end; j += 2) {
        int2 v0 = pack[j];
        int2 v1 = pack[j + 1];
        acc0 += gemb[(long)v0.x * 64 + lane];
        acc1 += gemb[(long)v1.x * 64 + lane];
        e0   += __int_as_float(v0.y);
        e1   += __int_as_float(v1.y);
    }
    if (j < end) {
        int2 v = pack[j];
        acc0 += gemb[(long)v.x * 64 + lane];
        e0   += __int_as_float(v.y);
    }
    out[(long)wid * 65 + lane] = acc0 + acc1;
    if (lane == 0) out[(long)wid * 65 + 64] = e0 + e1;
}

// Fallback (round-1 atomic version) in case ws_size is too small.
__global__ void atomic_fallback_kernel(const float* __restrict__ gemb,
                                       const float* __restrict__ efeat,
                                       const int* __restrict__ src,
                                       const int* __restrict__ dst,
                                       float* __restrict__ out, int E) {
    int eidx = blockIdx.x * 4 + (threadIdx.x >> 6);
    int lane = threadIdx.x & 63;
    if (eidx >= E) return;
    int s = src[eidx];
    int d = dst[eidx];
    float v = gemb[(long)s * 64 + lane];
    atomicAdd(&out[(long)d * 65 + lane], v);
    if (lane == 0) atomicAdd(&out[(long)d * 65 + 64], efeat[eidx]);
}

extern "C" void kernel_launch(void* const* d_in, const int* in_sizes, int n_in,
                              void* d_out, int out_size, void* d_ws, size_t ws_size,
                              hipStream_t stream) {
    const float* gemb  = (const float*)d_in[0];   // [N, 64]
    const float* efeat = (const float*)d_in[1];   // [E]
    const int*   src   = (const int*)d_in[2];     // [E]
    const int*   dst   = (const int*)d_in[3];     // [E]
    float*       out   = (float*)d_out;           // [N, 65]

    const int N = in_sizes[0] / 64;
    const int E = in_sizes[1];
    const int B = (N + SCAN_ELEMS - 1) / SCAN_ELEMS;   // scan blocks (<=128)

    // workspace layout (16B aligned chunks)
    size_t off_counts  = 0;
    size_t off_offsets = off_counts  + (((size_t)N * 4 + 15) & ~(size_t)15);
    size_t off_cursor  = off_offsets + (((size_t)(N + 1) * 4 + 15) & ~(size_t)15);
    size_t off_bsums   = off_cursor  + (((size_t)N * 4 + 15) & ~(size_t)15);
    size_t off_pack    = off_bsums   + (((size_t)B * 4 + 15) & ~(size_t)15);
    size_t needed      = off_pack    + (size_t)E * 8;

    if (ws_size < needed || B > 128) {
        hipMemsetAsync(d_out, 0, (size_t)out_size * sizeof(float), stream);
        int blocks = (E + 3) / 4;
        atomic_fallback_kernel<<<blocks, 256, 0, stream>>>(gemb, efeat, src, dst, out, E);
        return;
    }

    char* ws = (char*)d_ws;
    int*  counts  = (int*)(ws + off_counts);
    int*  offsets = (int*)(ws + off_offsets);
    int*  cursor  = (int*)(ws + off_cursor);
    int*  bsums   = (int*)(ws + off_bsums);
    int2* pack    = (int2*)(ws + off_pack);

    hipMemsetAsync(counts, 0, (size_t)N * 4, stream);

    int ethreads = (E + 3) / 4;
    int eblocks  = (ethreads + 255) / 256;
    hist_kernel<<<eblocks, 256, 0, stream>>>(dst, counts, E);

    scan_block_sums<<<B, SCAN_THREADS, 0, stream>>>(counts, bsums, N);
    scan_top<<<1, 128, 0, stream>>>(bsums, offsets + N, B);
    scan_final<<<B, SCAN_THREADS, 0, stream>>>(counts, bsums, offsets, cursor, N);

    scatter_kernel<<<eblocks, 256, 0, stream>>>(src, efeat, dst, cursor, pack, E);

    int nblocks = (N + 3) / 4;   // 4 waves (nodes) per 256-thread block
    gather_kernel<<<nblocks, 256, 0, stream>>>(gemb, pack, offsets, out, N);
}

// Round 4
// 180.611 us; speedup vs baseline: 2.6515x; 1.2753x over previous
//
#include <hip/hip_runtime.h>

// ---------------------------------------------------------------------------
// CSR build (hist -> hierarchical scan -> sliced scatter) + atomic-free
// gather-sum. Round-4 change: dst-sliced scatter (8 slices, blockIdx&7) so
// each slice's pack region is written from one XCD only -> partial-line
// writes combine in that XCD's L2 (WRITE_SIZE 77MB -> ~12MB predicted).
// ---------------------------------------------------------------------------

#define SCAN_ELEMS   1024   // counts per scan block
#define SCAN_THREADS 256    // 4 counts per thread
#define NSLICE       8

__global__ void hist_kernel(const int* __restrict__ dst, int* __restrict__ counts, int E) {
    int i = (blockIdx.x * blockDim.x + threadIdx.x) * 4;
    if (i + 3 < E) {
        int4 d = *(const int4*)(dst + i);
        atomicAdd(&counts[d.x], 1);
        atomicAdd(&counts[d.y], 1);
        atomicAdd(&counts[d.z], 1);
        atomicAdd(&counts[d.w], 1);
    } else {
        for (int k = i; k < E; ++k) atomicAdd(&counts[dst[k]], 1);
    }
}

// Phase A: per-block sums of 1024 counts each.
__global__ void scan_block_sums(const int* __restrict__ counts,
                                int* __restrict__ bsums, int N) {
    __shared__ int red[SCAN_THREADS];
    int tid  = threadIdx.x;
    int base = blockIdx.x * SCAN_ELEMS + tid * 4;
    int s = 0;
    if (base + 3 < N) {
        int4 c = *(const int4*)(counts + base);
        s = c.x + c.y + c.z + c.w;
    } else {
        int lim = min(base + 4, N);
        for (int k = base; k < lim; ++k) s += counts[k];
    }
    red[tid] = s;
    __syncthreads();
    for (int off = SCAN_THREADS / 2; off > 0; off >>= 1) {
        if (tid < off) red[tid] += red[tid + off];
        __syncthreads();
    }
    if (tid == 0) bsums[blockIdx.x] = red[0];
}

// Phase B: one small block scans the B block-sums (exclusive, in place),
// and writes offsets[N] = total (= E).
__global__ void scan_top(int* __restrict__ bsums, int* __restrict__ offsets_N, int B) {
    __shared__ int sh[128];
    int t = threadIdx.x;
    int v = (t < B) ? bsums[t] : 0;
    sh[t] = v;
    __syncthreads();
    for (int off = 1; off < 128; off <<= 1) {
        int u = (t >= off) ? sh[t - off] : 0;
        __syncthreads();
        sh[t] += u;
        __syncthreads();
    }
    if (t < B) bsums[t] = sh[t] - v;          // exclusive
    if (t == 127) offsets_N[0] = sh[127];     // total
}

// Phase C: local exclusive scan per block + block base -> offsets & cursor.
__global__ void scan_final(const int* __restrict__ counts,
                           const int* __restrict__ bsums,
                           int* __restrict__ offsets,
                           int* __restrict__ cursor, int N) {
    __shared__ int sh[SCAN_THREADS];
    int tid  = threadIdx.x;
    int base = blockIdx.x * SCAN_ELEMS + tid * 4;
    int4 c = make_int4(0, 0, 0, 0);
    if (base + 3 < N) {
        c = *(const int4*)(counts + base);
    } else {
        if (base + 0 < N) c.x = counts[base + 0];
        if (base + 1 < N) c.y = counts[base + 1];
        if (base + 2 < N) c.z = counts[base + 2];
    }
    int tsum = c.x + c.y + c.z + c.w;
    sh[tid] = tsum;
    __syncthreads();
    for (int off = 1; off < SCAN_THREADS; off <<= 1) {
        int u = (tid >= off) ? sh[tid - off] : 0;
        __syncthreads();
        sh[tid] += u;
        __syncthreads();
    }
    int excl = sh[tid] - tsum;
    int b0 = bsums[blockIdx.x] + excl;
    int4 o;
    o.x = b0;
    o.y = o.x + c.x;
    o.z = o.y + c.y;
    o.w = o.z + c.z;
    if (base + 3 < N) {
        *(int4*)(offsets + base) = o;
        *(int4*)(cursor  + base) = o;
    } else {
        if (base + 0 < N) { offsets[base + 0] = o.x; cursor[base + 0] = o.x; }
        if (base + 1 < N) { offsets[base + 1] = o.y; cursor[base + 1] = o.y; }
        if (base + 2 < N) { offsets[base + 2] = o.z; cursor[base + 2] = o.z; }
    }
}

// dst-sliced scatter: slice = blockIdx&7 handles dst in [s*slice_n,(s+1)*slice_n).
// Consecutive blockIdx round-robin across XCDs -> one XCD owns each slice's
// pack region -> partial-line writes combine in its L2. Correct regardless of
// the actual block->XCD mapping (only perf depends on it).
__global__ void scatter_sliced(const int* __restrict__ src,
                               const float* __restrict__ efeat,
                               const int* __restrict__ dst,
                               int* __restrict__ cursor,
                               int2* __restrict__ pack,
                               int E, int slice_n) {
    int s = blockIdx.x & (NSLICE - 1);
    int c = blockIdx.x >> 3;
    int i = (c * 256 + threadIdx.x) * 4;
    int lo = s * slice_n;
    int hi = lo + slice_n;

    if (i + 3 < E) {
        int4 d = *(const int4*)(dst + i);
        if (d.x >= lo && d.x < hi) {
            int p = atomicAdd(&cursor[d.x], 1);
            pack[p] = make_int2(src[i + 0], __float_as_int(efeat[i + 0]));
        }
        if (d.y >= lo && d.y < hi) {
            int p = atomicAdd(&cursor[d.y], 1);
            pack[p] = make_int2(src[i + 1], __float_as_int(efeat[i + 1]));
        }
        if (d.z >= lo && d.z < hi) {
            int p = atomicAdd(&cursor[d.z], 1);
            pack[p] = make_int2(src[i + 2], __float_as_int(efeat[i + 2]));
        }
        if (d.w >= lo && d.w < hi) {
            int p = atomicAdd(&cursor[d.w], 1);
            pack[p] = make_int2(src[i + 3], __float_as_int(efeat[i + 3]));
        }
    } else {
        for (int k = i; k < E; ++k) {
            int d = dst[k];
            if (d >= lo && d < hi) {
                int p = atomicAdd(&cursor[d], 1);
                pack[p] = make_int2(src[k], __float_as_int(efeat[k]));
            }
        }
    }
}

// One 64-lane wave per node; lane = feature index. Atomic-free, 4-way unroll.
__global__ void gather_kernel(const float* __restrict__ gemb,
                              const int2* __restrict__ pack,
                              const int* __restrict__ offsets,
                              float* __restrict__ out, int N) {
    int wid  = (blockIdx.x * blockDim.x + threadIdx.x) >> 6;
    int lane = threadIdx.x & 63;
    if (wid >= N) return;

    int beg = offsets[wid];
    int end = offsets[wid + 1];

    float acc0 = 0.f, acc1 = 0.f, acc2 = 0.f, acc3 = 0.f;
    float e0 = 0.f, e1 = 0.f, e2 = 0.f, e3 = 0.f;
    int j = beg;
    for (; j + 3 < end; j += 4) {
        int2 v0 = pack[j];
        int2 v1 = pack[j + 1];
        int2 v2 = pack[j + 2];
        int2 v3 = pack[j + 3];
        acc0 += gemb[(long)v0.x * 64 + lane];
        acc1 += gemb[(long)v1.x * 64 + lane];
        acc2 += gemb[(long)v2.x * 64 + lane];
        acc3 += gemb[(long)v3.x * 64 + lane];
        e0 += __int_as_float(v0.y);
        e1 += __int_as_float(v1.y);
        e2 += __int_as_float(v2.y);
        e3 += __int_as_float(v3.y);
    }
    for (; j < end; ++j) {
        int2 v = pack[j];
        acc0 += gemb[(long)v.x * 64 + lane];
        e0   += __int_as_float(v.y);
    }
    out[(long)wid * 65 + lane] = (acc0 + acc1) + (acc2 + acc3);
    if (lane == 0) out[(long)wid * 65 + 64] = (e0 + e1) + (e2 + e3);
}

// Fallback (round-1 atomic version) in case ws_size is too small.
__global__ void atomic_fallback_kernel(const float* __restrict__ gemb,
                                       const float* __restrict__ efeat,
                                       const int* __restrict__ src,
                                       const int* __restrict__ dst,
                                       float* __restrict__ out, int E) {
    int eidx = blockIdx.x * 4 + (threadIdx.x >> 6);
    int lane = threadIdx.x & 63;
    if (eidx >= E) return;
    int s = src[eidx];
    int d = dst[eidx];
    float v = gemb[(long)s * 64 + lane];
    atomicAdd(&out[(long)d * 65 + lane], v);
    if (lane == 0) atomicAdd(&out[(long)d * 65 + 64], efeat[eidx]);
}

extern "C" void kernel_launch(void* const* d_in, const int* in_sizes, int n_in,
                              void* d_out, int out_size, void* d_ws, size_t ws_size,
                              hipStream_t stream) {
    const float* gemb  = (const float*)d_in[0];   // [N, 64]
    const float* efeat = (const float*)d_in[1];   // [E]
    const int*   src   = (const int*)d_in[2];     // [E]
    const int*   dst   = (const int*)d_in[3];     // [E]
    float*       out   = (float*)d_out;           // [N, 65]

    const int N = in_sizes[0] / 64;
    const int E = in_sizes[1];
    const int B = (N + SCAN_ELEMS - 1) / SCAN_ELEMS;   // scan blocks (<=128)

    // workspace layout (16B aligned chunks)
    size_t off_counts  = 0;
    size_t off_offsets = off_counts  + (((size_t)N * 4 + 15) & ~(size_t)15);
    size_t off_cursor  = off_offsets + (((size_t)(N + 1) * 4 + 15) & ~(size_t)15);
    size_t off_bsums   = off_cursor  + (((size_t)N * 4 + 15) & ~(size_t)15);
    size_t off_pack    = off_bsums   + (((size_t)B * 4 + 15) & ~(size_t)15);
    size_t needed      = off_pack    + (size_t)E * 8;

    if (ws_size < needed || B > 128) {
        hipMemsetAsync(d_out, 0, (size_t)out_size * sizeof(float), stream);
        int blocks = (E + 3) / 4;
        atomic_fallback_kernel<<<blocks, 256, 0, stream>>>(gemb, efeat, src, dst, out, E);
        return;
    }

    char* ws = (char*)d_ws;
    int*  counts  = (int*)(ws + off_counts);
    int*  offsets = (int*)(ws + off_offsets);
    int*  cursor  = (int*)(ws + off_cursor);
    int*  bsums   = (int*)(ws + off_bsums);
    int2* pack    = (int2*)(ws + off_pack);

    hipMemsetAsync(counts, 0, (size_t)N * 4, stream);

    int ethreads = (E + 3) / 4;
    int eblocks  = (ethreads + 255) / 256;
    hist_kernel<<<eblocks, 256, 0, stream>>>(dst, counts, E);

    scan_block_sums<<<B, SCAN_THREADS, 0, stream>>>(counts, bsums, N);
    scan_top<<<1, 128, 0, stream>>>(bsums, offsets + N, B);
    scan_final<<<B, SCAN_THREADS, 0, stream>>>(counts, bsums, offsets, cursor, N);

    int slice_n = (N + NSLICE - 1) / NSLICE;
    scatter_sliced<<<eblocks * NSLICE, 256, 0, stream>>>(src, efeat, dst, cursor, pack, E, slice_n);

    int nblocks = (N + 3) / 4;   // 4 waves (nodes) per 256-thread block
    gather_kernel<<<nblocks, 256, 0, stream>>>(gemb, pack, offsets, out, N);
}